// Round 1
// 663.063 us; speedup vs baseline: 1.2209x; 1.2209x over previous
//
#include <hip/hip_runtime.h>

#define N_ITEMS   100000
#define N_BASKETS 50000
#define NNZ       1000000
#define D         128
#define NUM_LAYER 3

#define SCAN_BLOCKS 256
#define SCAN_TPB    256

// ---------------- fused histogram over both matrices ----------------
__global__ void k_hist2(const int* __restrict__ b_rows, const int* __restrict__ i_rows,
                        int* __restrict__ b_count, int* __restrict__ i_count) {
    int i = blockIdx.x * blockDim.x + threadIdx.x;
    int stride = gridDim.x * blockDim.x;
    for (; i < 2 * NNZ; i += stride) {
        if (i < NNZ) atomicAdd(&b_count[b_rows[i]], 1);
        else         atomicAdd(&i_count[i_rows[i - NNZ]], 1);
    }
}

// ---------------- hierarchical exclusive scan, both arrays in one pass ----------------
// blocks [0,SCAN_BLOCKS): basket counts; [SCAN_BLOCKS,2*SCAN_BLOCKS): item counts
__global__ void k_chunk_sums2(const int* __restrict__ b_in, const int* __restrict__ i_in,
                              int* __restrict__ bsums) {
    __shared__ int lds[SCAN_TPB];
    int blk = blockIdx.x;
    const int* in; int n; int b;
    if (blk < SCAN_BLOCKS) { in = b_in; n = N_BASKETS + 1; b = blk; }
    else                   { in = i_in; n = N_ITEMS + 1;   b = blk - SCAN_BLOCKS; }
    int chunk = (n + SCAN_BLOCKS - 1) / SCAN_BLOCKS;
    int s = b * chunk;
    int e = min(s + chunk, n);
    int acc = 0;
    for (int i = s + (int)threadIdx.x; i < e; i += SCAN_TPB) acc += in[i];
    lds[threadIdx.x] = acc;
    __syncthreads();
    for (int o = SCAN_TPB / 2; o > 0; o >>= 1) {
        if ((int)threadIdx.x < o) lds[threadIdx.x] += lds[threadIdx.x + o];
        __syncthreads();
    }
    if (threadIdx.x == 0) bsums[blk] = lds[0];
}

__global__ void k_exscan2(int* __restrict__ bsums) {
    // 2 blocks, each exclusive-scans its own SCAN_BLOCKS region
    __shared__ int lds[SCAN_TPB];
    int* p = bsums + blockIdx.x * SCAN_BLOCKS;
    int v = p[threadIdx.x];
    lds[threadIdx.x] = v;
    __syncthreads();
    for (int o = 1; o < SCAN_TPB; o <<= 1) {
        int t = ((int)threadIdx.x >= o) ? lds[threadIdx.x - o] : 0;
        __syncthreads();
        lds[threadIdx.x] += t;
        __syncthreads();
    }
    p[threadIdx.x] = lds[threadIdx.x] - v; // exclusive
}

__global__ void k_scan_write2(const int* __restrict__ b_in, const int* __restrict__ i_in,
                              const int* __restrict__ bsums,
                              int* __restrict__ b_out, int* __restrict__ i_out) {
    __shared__ int lds[SCAN_TPB];
    int blk = blockIdx.x;
    const int* in; int* out; int n; int b;
    if (blk < SCAN_BLOCKS) { in = b_in; out = b_out; n = N_BASKETS + 1; b = blk; }
    else                   { in = i_in; out = i_out; n = N_ITEMS + 1;   b = blk - SCAN_BLOCKS; }
    int chunk = (n + SCAN_BLOCKS - 1) / SCAN_BLOCKS;
    int s = b * chunk;
    int e = min(s + chunk, n);
    int carry = bsums[blk];
    for (int base = s; base < e; base += SCAN_TPB) {
        int i = base + (int)threadIdx.x;
        int v = (i < e) ? in[i] : 0;
        lds[threadIdx.x] = v;
        __syncthreads();
        for (int o = 1; o < SCAN_TPB; o <<= 1) {
            int t = ((int)threadIdx.x >= o) ? lds[threadIdx.x - o] : 0;
            __syncthreads();
            lds[threadIdx.x] += t;
            __syncthreads();
        }
        if (i < e) out[i] = carry + lds[threadIdx.x] - v;
        int tot = lds[SCAN_TPB - 1];
        __syncthreads();
        carry += tot;
    }
}

// ---------------- fused scatter into packed (col,val) CSR ----------------
__global__ void k_scatter2(const int* __restrict__ b_rows, const int* __restrict__ b_cols,
                           const float* __restrict__ b_vals,
                           const int* __restrict__ i_rows, const int* __restrict__ i_cols,
                           const float* __restrict__ i_vals,
                           const int* __restrict__ b_row_ptr, const int* __restrict__ i_row_ptr,
                           int* __restrict__ b_fill, int* __restrict__ i_fill,
                           int2* __restrict__ b_ev, int2* __restrict__ i_ev) {
    int i = blockIdx.x * blockDim.x + threadIdx.x;
    int stride = gridDim.x * blockDim.x;
    for (; i < 2 * NNZ; i += stride) {
        if (i < NNZ) {
            int r = b_rows[i];
            int pos = b_row_ptr[r] + atomicAdd(&b_fill[r], 1);
            b_ev[pos] = make_int2(b_cols[i], __float_as_int(b_vals[i]));
        } else {
            int j = i - NNZ;
            int r = i_rows[j];
            int pos = i_row_ptr[r] + atomicAdd(&i_fill[r], 1);
            i_ev[pos] = make_int2(i_cols[j], __float_as_int(i_vals[j]));
        }
    }
}

// ---------------- CSR SpMM: one 64-lane wave per row, 4-deep pipelined gather ------
// MODE 0: out = acc
// MODE 1: out = acc; sum = acc                (basket layer 1: kills memset + rmw read)
// MODE 2: out = acc; sum += acc               (basket layer 2)
// MODE 3: out = acc; sum = (sum + acc)/3      (basket layer 3, scale fused)
// MODE 4: out = (a0 + a1 + a2 + acc)/4        (item layer 3, final sum+scale fused)
template<int MODE>
__global__ __launch_bounds__(256) void k_spmm(const int* __restrict__ row_ptr,
                                              const int2* __restrict__ ev,
                                              const float* __restrict__ dense,
                                              float* out, float* sum,
                                              const float* a0, const float* a1,
                                              const float* a2,
                                              int n_rows) {
    int wv   = threadIdx.x >> 6;
    int lane = threadIdx.x & 63;
    int row  = blockIdx.x * 4 + wv;
    if (row >= n_rows) return;
    int beg = row_ptr[row];
    int end = row_ptr[row + 1];
    // uniform per wave -> scalarize loop control
    beg = __builtin_amdgcn_readfirstlane(beg);
    end = __builtin_amdgcn_readfirstlane(end);

    const char* dbase = reinterpret_cast<const char*>(dense) + (size_t)lane * 8;
    float ax = 0.f, ay = 0.f;
    int e = beg;
    // 4 outstanding 512B gathers per wave
    for (; e + 4 <= end; e += 4) {
        int2 p0 = ev[e + 0], p1 = ev[e + 1], p2 = ev[e + 2], p3 = ev[e + 3];
        float2 d0 = *reinterpret_cast<const float2*>(dbase + ((size_t)p0.x << 9));
        float2 d1 = *reinterpret_cast<const float2*>(dbase + ((size_t)p1.x << 9));
        float2 d2 = *reinterpret_cast<const float2*>(dbase + ((size_t)p2.x << 9));
        float2 d3 = *reinterpret_cast<const float2*>(dbase + ((size_t)p3.x << 9));
        float v0 = __int_as_float(p0.y), v1 = __int_as_float(p1.y);
        float v2 = __int_as_float(p2.y), v3 = __int_as_float(p3.y);
        ax = fmaf(v0, d0.x, ax); ay = fmaf(v0, d0.y, ay);
        ax = fmaf(v1, d1.x, ax); ay = fmaf(v1, d1.y, ay);
        ax = fmaf(v2, d2.x, ax); ay = fmaf(v2, d2.y, ay);
        ax = fmaf(v3, d3.x, ax); ay = fmaf(v3, d3.y, ay);
    }
    if (e + 2 <= end) {
        int2 p0 = ev[e], p1 = ev[e + 1];
        float2 d0 = *reinterpret_cast<const float2*>(dbase + ((size_t)p0.x << 9));
        float2 d1 = *reinterpret_cast<const float2*>(dbase + ((size_t)p1.x << 9));
        float v0 = __int_as_float(p0.y), v1 = __int_as_float(p1.y);
        ax = fmaf(v0, d0.x, ax); ay = fmaf(v0, d0.y, ay);
        ax = fmaf(v1, d1.x, ax); ay = fmaf(v1, d1.y, ay);
        e += 2;
    }
    if (e < end) {
        int2 p0 = ev[e];
        float2 d0 = *reinterpret_cast<const float2*>(dbase + ((size_t)p0.x << 9));
        float v0 = __int_as_float(p0.y);
        ax = fmaf(v0, d0.x, ax); ay = fmaf(v0, d0.y, ay);
    }

    size_t o = (size_t)row * D + (size_t)lane * 2;
    float2 r = make_float2(ax, ay);
    if (MODE == 0) {
        *reinterpret_cast<float2*>(out + o) = r;
    } else if (MODE == 1) {
        *reinterpret_cast<float2*>(out + o) = r;
        *reinterpret_cast<float2*>(sum + o) = r;
    } else if (MODE == 2) {
        *reinterpret_cast<float2*>(out + o) = r;
        float2 s = *reinterpret_cast<const float2*>(sum + o);
        s.x += r.x; s.y += r.y;
        *reinterpret_cast<float2*>(sum + o) = s;
    } else if (MODE == 3) {
        *reinterpret_cast<float2*>(out + o) = r;
        float2 s = *reinterpret_cast<const float2*>(sum + o);
        s.x = (s.x + r.x) * (1.0f / 3.0f);
        s.y = (s.y + r.y) * (1.0f / 3.0f);
        *reinterpret_cast<float2*>(sum + o) = s;
    } else { // MODE 4
        float2 s0 = *reinterpret_cast<const float2*>(a0 + o);
        float2 s1 = *reinterpret_cast<const float2*>(a1 + o);
        float2 s2 = *reinterpret_cast<const float2*>(a2 + o);
        r.x = (s0.x + s1.x + s2.x + r.x) * 0.25f;
        r.y = (s0.y + s1.y + s2.y + r.y) * 0.25f;
        *reinterpret_cast<float2*>(out + o) = r;
    }
}

extern "C" void kernel_launch(void* const* d_in, const int* in_sizes, int n_in,
                              void* d_out, int out_size, void* d_ws, size_t ws_size,
                              hipStream_t stream) {
    const float* x      = (const float*)d_in[0];
    const int*   b_rows = (const int*)  d_in[1];
    const int*   b_cols = (const int*)  d_in[2];
    const float* b_vals = (const float*)d_in[3];
    const int*   i_rows = (const int*)  d_in[4];
    const int*   i_cols = (const int*)  d_in[5];
    const float* i_vals = (const float*)d_in[6];

    float* out        = (float*)d_out;
    float* out_item   = out;                              // [N_ITEMS * D]; doubles as cur1 storage
    float* out_basket = out + (size_t)N_ITEMS * D;        // [N_BASKETS * D]

    // -------- workspace layout (≈94.6 MB, same footprint as previous version) -----
    char* ws = (char*)d_ws;
    size_t off = 0;
    auto alloc = [&](size_t bytes) -> char* {
        char* p = ws + off;
        off = (off + bytes + 255) & ~(size_t)255;
        return p;
    };
    int*   cnt       = (int*)  alloc((size_t)(N_BASKETS + N_ITEMS + 2) * sizeof(int));
    int*   b_count   = cnt;
    int*   i_count   = cnt + (N_BASKETS + 1);
    int*   b_row_ptr = (int*)  alloc((N_BASKETS + 1) * sizeof(int));
    int*   i_row_ptr = (int*)  alloc((N_ITEMS + 1) * sizeof(int));
    int*   fills     = (int*)  alloc((size_t)(N_BASKETS + N_ITEMS) * sizeof(int));
    int*   b_fill    = fills;
    int*   i_fill    = fills + N_BASKETS;
    int*   bsums     = (int*)  alloc(2 * SCAN_BLOCKS * sizeof(int));
    int2*  b_ev      = (int2*) alloc((size_t)NNZ * sizeof(int2));
    int2*  i_ev      = (int2*) alloc((size_t)NNZ * sizeof(int2));
    float* basket_buf= (float*)alloc((size_t)N_BASKETS * D * sizeof(float));
    float* cur2      = (float*)alloc((size_t)N_ITEMS * D * sizeof(float));
    (void)ws_size; (void)in_sizes; (void)n_in; (void)out_size;

    // -------- build both CSRs in one fused pipeline --------
    hipMemsetAsync(cnt, 0, (size_t)(N_BASKETS + N_ITEMS + 2) * sizeof(int), stream);
    hipMemsetAsync(fills, 0, (size_t)(N_BASKETS + N_ITEMS) * sizeof(int), stream);
    k_hist2<<<2048, 256, 0, stream>>>(b_rows, i_rows, b_count, i_count);
    k_chunk_sums2<<<2 * SCAN_BLOCKS, SCAN_TPB, 0, stream>>>(b_count, i_count, bsums);
    k_exscan2<<<2, SCAN_TPB, 0, stream>>>(bsums);
    k_scan_write2<<<2 * SCAN_BLOCKS, SCAN_TPB, 0, stream>>>(b_count, i_count, bsums,
                                                            b_row_ptr, i_row_ptr);
    k_scatter2<<<2048, 256, 0, stream>>>(b_rows, b_cols, b_vals,
                                         i_rows, i_cols, i_vals,
                                         b_row_ptr, i_row_ptr, b_fill, i_fill,
                                         b_ev, i_ev);

    const int GB = (N_BASKETS + 3) / 4;   // 12500 blocks, 4 rows/block (1 wave each)
    const int GI = (N_ITEMS + 3) / 4;     // 25000 blocks

    // -------- layer 1 --------
    // basket1 = B @ x ; out_basket := basket1 (dual write, no memset, no rmw read)
    k_spmm<1><<<GB, 256, 0, stream>>>(b_row_ptr, b_ev, x, basket_buf, out_basket,
                                      nullptr, nullptr, nullptr, N_BASKETS);
    // cur1 = I @ basket1 ; stored in out_item region (free until final pass)
    k_spmm<0><<<GI, 256, 0, stream>>>(i_row_ptr, i_ev, basket_buf, out_item, nullptr,
                                      nullptr, nullptr, nullptr, N_ITEMS);
    // -------- layer 2 --------
    // basket2 = B @ cur1 ; out_basket += basket2
    k_spmm<2><<<GB, 256, 0, stream>>>(b_row_ptr, b_ev, out_item, basket_buf, out_basket,
                                      nullptr, nullptr, nullptr, N_BASKETS);
    // cur2 = I @ basket2
    k_spmm<0><<<GI, 256, 0, stream>>>(i_row_ptr, i_ev, basket_buf, cur2, nullptr,
                                      nullptr, nullptr, nullptr, N_ITEMS);
    // -------- layer 3 --------
    // basket3 = B @ cur2 ; out_basket = (out_basket + basket3)/3  (scale fused)
    k_spmm<3><<<GB, 256, 0, stream>>>(b_row_ptr, b_ev, cur2, basket_buf, out_basket,
                                      nullptr, nullptr, nullptr, N_BASKETS);
    // out_item = (x + cur1 + cur2 + I @ basket3)/4  (final sum + scale fused; cur3 never hits DRAM)
    k_spmm<4><<<GI, 256, 0, stream>>>(i_row_ptr, i_ev, basket_buf, out_item, nullptr,
                                      x, out_item, cur2, N_ITEMS);
}

// Round 2
// 657.081 us; speedup vs baseline: 1.2320x; 1.0091x over previous
//
#include <hip/hip_runtime.h>

#define N_ITEMS   100000
#define N_BASKETS 50000
#define NNZ       1000000
#define D         128
#define NUM_LAYER 3

#define SCAN_BLOCKS 256
#define SCAN_TPB    256

#define NPART      8      // destination partitions == XCDs
#define PART_GRID  2048   // 256 blocks per partition group

// ---------------- destination-partitioned histogram ----------------
// group g = blockIdx & 7 (block->XCD round-robin heuristic) only counts rows in
// partition g, so each count line is owned by one XCD's L2 -> written back once.
__global__ void k_hist2(const int* __restrict__ b_rows, const int* __restrict__ i_rows,
                        int* __restrict__ b_count, int* __restrict__ i_count) {
    int part = blockIdx.x & (NPART - 1);
    int blk  = blockIdx.x >> 3;
    int tid  = blk * blockDim.x + threadIdx.x;
    int stride = (PART_GRID / NPART) * blockDim.x;
    const int PB = (N_BASKETS + NPART - 1) / NPART;   // 6250
    const int PI = (N_ITEMS + NPART - 1) / NPART;     // 12500
    int blo = part * PB, bhi = blo + PB;
    for (int i = tid; i < NNZ; i += stride) {
        int r = b_rows[i];
        if (r >= blo && r < bhi) atomicAdd(&b_count[r], 1);
    }
    int ilo = part * PI, ihi = ilo + PI;
    for (int i = tid; i < NNZ; i += stride) {
        int r = i_rows[i];
        if (r >= ilo && r < ihi) atomicAdd(&i_count[r], 1);
    }
}

// ---------------- hierarchical exclusive scan, both arrays in one pass ----------------
__global__ void k_chunk_sums2(const int* __restrict__ b_in, const int* __restrict__ i_in,
                              int* __restrict__ bsums) {
    __shared__ int lds[SCAN_TPB];
    int blk = blockIdx.x;
    const int* in; int n; int b;
    if (blk < SCAN_BLOCKS) { in = b_in; n = N_BASKETS + 1; b = blk; }
    else                   { in = i_in; n = N_ITEMS + 1;   b = blk - SCAN_BLOCKS; }
    int chunk = (n + SCAN_BLOCKS - 1) / SCAN_BLOCKS;
    int s = b * chunk;
    int e = min(s + chunk, n);
    int acc = 0;
    for (int i = s + (int)threadIdx.x; i < e; i += SCAN_TPB) acc += in[i];
    lds[threadIdx.x] = acc;
    __syncthreads();
    for (int o = SCAN_TPB / 2; o > 0; o >>= 1) {
        if ((int)threadIdx.x < o) lds[threadIdx.x] += lds[threadIdx.x + o];
        __syncthreads();
    }
    if (threadIdx.x == 0) bsums[blk] = lds[0];
}

__global__ void k_exscan2(int* __restrict__ bsums) {
    __shared__ int lds[SCAN_TPB];
    int* p = bsums + blockIdx.x * SCAN_BLOCKS;
    int v = p[threadIdx.x];
    lds[threadIdx.x] = v;
    __syncthreads();
    for (int o = 1; o < SCAN_TPB; o <<= 1) {
        int t = ((int)threadIdx.x >= o) ? lds[threadIdx.x - o] : 0;
        __syncthreads();
        lds[threadIdx.x] += t;
        __syncthreads();
    }
    p[threadIdx.x] = lds[threadIdx.x] - v; // exclusive
}

// also seeds fill[] = row_ptr[] so the scatter needs only one atomicAdd
__global__ void k_scan_write2(const int* __restrict__ b_in, const int* __restrict__ i_in,
                              const int* __restrict__ bsums,
                              int* __restrict__ b_out, int* __restrict__ i_out,
                              int* __restrict__ b_fill, int* __restrict__ i_fill) {
    __shared__ int lds[SCAN_TPB];
    int blk = blockIdx.x;
    const int* in; int* out; int* fill; int n; int b;
    if (blk < SCAN_BLOCKS) { in = b_in; out = b_out; fill = b_fill; n = N_BASKETS + 1; b = blk; }
    else                   { in = i_in; out = i_out; fill = i_fill; n = N_ITEMS + 1;   b = blk - SCAN_BLOCKS; }
    int chunk = (n + SCAN_BLOCKS - 1) / SCAN_BLOCKS;
    int s = b * chunk;
    int e = min(s + chunk, n);
    int carry = bsums[blk];
    for (int base = s; base < e; base += SCAN_TPB) {
        int i = base + (int)threadIdx.x;
        int v = (i < e) ? in[i] : 0;
        lds[threadIdx.x] = v;
        __syncthreads();
        for (int o = 1; o < SCAN_TPB; o <<= 1) {
            int t = ((int)threadIdx.x >= o) ? lds[threadIdx.x - o] : 0;
            __syncthreads();
            lds[threadIdx.x] += t;
            __syncthreads();
        }
        if (i < e) {
            int val = carry + lds[threadIdx.x] - v;
            out[i] = val;
            if (i < n - 1) fill[i] = val;   // seed fill cursor
        }
        int tot = lds[SCAN_TPB - 1];
        __syncthreads();
        carry += tot;
    }
}

// ---------------- destination-partitioned scatter into packed (col,val) CSR --------
// fill[] pre-seeded with row_ptr, so pos = atomicAdd(&fill[r],1) directly.
__global__ void k_scatter2(const int* __restrict__ b_rows, const int* __restrict__ b_cols,
                           const float* __restrict__ b_vals,
                           const int* __restrict__ i_rows, const int* __restrict__ i_cols,
                           const float* __restrict__ i_vals,
                           int* __restrict__ b_fill, int* __restrict__ i_fill,
                           int2* __restrict__ b_ev, int2* __restrict__ i_ev) {
    int part = blockIdx.x & (NPART - 1);
    int blk  = blockIdx.x >> 3;
    int tid  = blk * blockDim.x + threadIdx.x;
    int stride = (PART_GRID / NPART) * blockDim.x;
    const int PB = (N_BASKETS + NPART - 1) / NPART;
    const int PI = (N_ITEMS + NPART - 1) / NPART;
    int blo = part * PB, bhi = blo + PB;
    for (int i = tid; i < NNZ; i += stride) {
        int r = b_rows[i];
        if (r >= blo && r < bhi) {
            int pos = atomicAdd(&b_fill[r], 1);
            b_ev[pos] = make_int2(b_cols[i], __float_as_int(b_vals[i]));
        }
    }
    int ilo = part * PI, ihi = ilo + PI;
    for (int i = tid; i < NNZ; i += stride) {
        int r = i_rows[i];
        if (r >= ilo && r < ihi) {
            int pos = atomicAdd(&i_fill[r], 1);
            i_ev[pos] = make_int2(i_cols[i], __float_as_int(i_vals[i]));
        }
    }
}

// ---------------- CSR SpMM: one 64-lane wave per row, 4-deep pipelined gather ------
// MODE 0: out = acc
// MODE 1: out = acc; sum = acc
// MODE 2: out = acc; sum += acc
// MODE 3: out = acc; sum = (sum + acc)/3
// MODE 4: out = (a0 + a1 + a2 + acc)/4
template<int MODE>
__global__ __launch_bounds__(256) void k_spmm(const int* __restrict__ row_ptr,
                                              const int2* __restrict__ ev,
                                              const float* __restrict__ dense,
                                              float* out, float* sum,
                                              const float* a0, const float* a1,
                                              const float* a2,
                                              int n_rows) {
    int wv   = threadIdx.x >> 6;
    int lane = threadIdx.x & 63;
    int row  = blockIdx.x * 4 + wv;
    if (row >= n_rows) return;
    int beg = row_ptr[row];
    int end = row_ptr[row + 1];
    beg = __builtin_amdgcn_readfirstlane(beg);
    end = __builtin_amdgcn_readfirstlane(end);

    const char* dbase = reinterpret_cast<const char*>(dense) + (size_t)lane * 8;
    float ax = 0.f, ay = 0.f;
    int e = beg;
    for (; e + 4 <= end; e += 4) {
        int2 p0 = ev[e + 0], p1 = ev[e + 1], p2 = ev[e + 2], p3 = ev[e + 3];
        float2 d0 = *reinterpret_cast<const float2*>(dbase + ((size_t)p0.x << 9));
        float2 d1 = *reinterpret_cast<const float2*>(dbase + ((size_t)p1.x << 9));
        float2 d2 = *reinterpret_cast<const float2*>(dbase + ((size_t)p2.x << 9));
        float2 d3 = *reinterpret_cast<const float2*>(dbase + ((size_t)p3.x << 9));
        float v0 = __int_as_float(p0.y), v1 = __int_as_float(p1.y);
        float v2 = __int_as_float(p2.y), v3 = __int_as_float(p3.y);
        ax = fmaf(v0, d0.x, ax); ay = fmaf(v0, d0.y, ay);
        ax = fmaf(v1, d1.x, ax); ay = fmaf(v1, d1.y, ay);
        ax = fmaf(v2, d2.x, ax); ay = fmaf(v2, d2.y, ay);
        ax = fmaf(v3, d3.x, ax); ay = fmaf(v3, d3.y, ay);
    }
    if (e + 2 <= end) {
        int2 p0 = ev[e], p1 = ev[e + 1];
        float2 d0 = *reinterpret_cast<const float2*>(dbase + ((size_t)p0.x << 9));
        float2 d1 = *reinterpret_cast<const float2*>(dbase + ((size_t)p1.x << 9));
        float v0 = __int_as_float(p0.y), v1 = __int_as_float(p1.y);
        ax = fmaf(v0, d0.x, ax); ay = fmaf(v0, d0.y, ay);
        ax = fmaf(v1, d1.x, ax); ay = fmaf(v1, d1.y, ay);
        e += 2;
    }
    if (e < end) {
        int2 p0 = ev[e];
        float2 d0 = *reinterpret_cast<const float2*>(dbase + ((size_t)p0.x << 9));
        float v0 = __int_as_float(p0.y);
        ax = fmaf(v0, d0.x, ax); ay = fmaf(v0, d0.y, ay);
    }

    size_t o = (size_t)row * D + (size_t)lane * 2;
    float2 r = make_float2(ax, ay);
    if (MODE == 0) {
        *reinterpret_cast<float2*>(out + o) = r;
    } else if (MODE == 1) {
        *reinterpret_cast<float2*>(out + o) = r;
        *reinterpret_cast<float2*>(sum + o) = r;
    } else if (MODE == 2) {
        *reinterpret_cast<float2*>(out + o) = r;
        float2 s = *reinterpret_cast<const float2*>(sum + o);
        s.x += r.x; s.y += r.y;
        *reinterpret_cast<float2*>(sum + o) = s;
    } else if (MODE == 3) {
        *reinterpret_cast<float2*>(out + o) = r;
        float2 s = *reinterpret_cast<const float2*>(sum + o);
        s.x = (s.x + r.x) * (1.0f / 3.0f);
        s.y = (s.y + r.y) * (1.0f / 3.0f);
        *reinterpret_cast<float2*>(sum + o) = s;
    } else { // MODE 4
        float2 s0 = *reinterpret_cast<const float2*>(a0 + o);
        float2 s1 = *reinterpret_cast<const float2*>(a1 + o);
        float2 s2 = *reinterpret_cast<const float2*>(a2 + o);
        r.x = (s0.x + s1.x + s2.x + r.x) * 0.25f;
        r.y = (s0.y + s1.y + s2.y + r.y) * 0.25f;
        *reinterpret_cast<float2*>(out + o) = r;
    }
}

extern "C" void kernel_launch(void* const* d_in, const int* in_sizes, int n_in,
                              void* d_out, int out_size, void* d_ws, size_t ws_size,
                              hipStream_t stream) {
    const float* x      = (const float*)d_in[0];
    const int*   b_rows = (const int*)  d_in[1];
    const int*   b_cols = (const int*)  d_in[2];
    const float* b_vals = (const float*)d_in[3];
    const int*   i_rows = (const int*)  d_in[4];
    const int*   i_cols = (const int*)  d_in[5];
    const float* i_vals = (const float*)d_in[6];

    float* out        = (float*)d_out;
    float* out_item   = out;                              // [N_ITEMS * D]; doubles as cur1 storage
    float* out_basket = out + (size_t)N_ITEMS * D;        // [N_BASKETS * D]

    char* ws = (char*)d_ws;
    size_t off = 0;
    auto alloc = [&](size_t bytes) -> char* {
        char* p = ws + off;
        off = (off + bytes + 255) & ~(size_t)255;
        return p;
    };
    int*   cnt       = (int*)  alloc((size_t)(N_BASKETS + N_ITEMS + 2) * sizeof(int));
    int*   b_count   = cnt;
    int*   i_count   = cnt + (N_BASKETS + 1);
    int*   b_row_ptr = (int*)  alloc((N_BASKETS + 1) * sizeof(int));
    int*   i_row_ptr = (int*)  alloc((N_ITEMS + 1) * sizeof(int));
    int*   fills     = (int*)  alloc((size_t)(N_BASKETS + N_ITEMS) * sizeof(int));
    int*   b_fill    = fills;
    int*   i_fill    = fills + N_BASKETS;
    int*   bsums     = (int*)  alloc(2 * SCAN_BLOCKS * sizeof(int));
    int2*  b_ev      = (int2*) alloc((size_t)NNZ * sizeof(int2));
    int2*  i_ev      = (int2*) alloc((size_t)NNZ * sizeof(int2));
    float* basket_buf= (float*)alloc((size_t)N_BASKETS * D * sizeof(float));
    float* cur2      = (float*)alloc((size_t)N_ITEMS * D * sizeof(float));
    (void)ws_size; (void)in_sizes; (void)n_in; (void)out_size;

    // -------- build both CSRs (destination-partitioned, XCD-pinned) --------
    hipMemsetAsync(cnt, 0, (size_t)(N_BASKETS + N_ITEMS + 2) * sizeof(int), stream);
    k_hist2<<<PART_GRID, 256, 0, stream>>>(b_rows, i_rows, b_count, i_count);
    k_chunk_sums2<<<2 * SCAN_BLOCKS, SCAN_TPB, 0, stream>>>(b_count, i_count, bsums);
    k_exscan2<<<2, SCAN_TPB, 0, stream>>>(bsums);
    k_scan_write2<<<2 * SCAN_BLOCKS, SCAN_TPB, 0, stream>>>(b_count, i_count, bsums,
                                                            b_row_ptr, i_row_ptr,
                                                            b_fill, i_fill);
    k_scatter2<<<PART_GRID, 256, 0, stream>>>(b_rows, b_cols, b_vals,
                                              i_rows, i_cols, i_vals,
                                              b_fill, i_fill, b_ev, i_ev);

    const int GB = (N_BASKETS + 3) / 4;
    const int GI = (N_ITEMS + 3) / 4;

    // -------- layer 1 --------
    k_spmm<1><<<GB, 256, 0, stream>>>(b_row_ptr, b_ev, x, basket_buf, out_basket,
                                      nullptr, nullptr, nullptr, N_BASKETS);
    k_spmm<0><<<GI, 256, 0, stream>>>(i_row_ptr, i_ev, basket_buf, out_item, nullptr,
                                      nullptr, nullptr, nullptr, N_ITEMS);
    // -------- layer 2 --------
    k_spmm<2><<<GB, 256, 0, stream>>>(b_row_ptr, b_ev, out_item, basket_buf, out_basket,
                                      nullptr, nullptr, nullptr, N_BASKETS);
    k_spmm<0><<<GI, 256, 0, stream>>>(i_row_ptr, i_ev, basket_buf, cur2, nullptr,
                                      nullptr, nullptr, nullptr, N_ITEMS);
    // -------- layer 3 --------
    k_spmm<3><<<GB, 256, 0, stream>>>(b_row_ptr, b_ev, cur2, basket_buf, out_basket,
                                      nullptr, nullptr, nullptr, N_BASKETS);
    k_spmm<4><<<GI, 256, 0, stream>>>(i_row_ptr, i_ev, basket_buf, out_item, nullptr,
                                      x, out_item, cur2, N_ITEMS);
}